// Round 12
// baseline (533.496 us; speedup 1.0000x reference)
//
#include <hip/hip_runtime.h>
#include <cstdint>
#include <cstddef>

#define N_NODES 50000
#define N_EDGES 600000
#define NLAYER  4
#define NGRAPH  64
#define SCAN_NB 196   // ceil(50000/256)
#define NBLK_MLP ((N_NODES + 127) / 128)   // 391, 128-row MLP tiles
#define RED_B    ((NBLK_MLP + 12) / 13)    // 31 reduce blocks x 13 partials

typedef unsigned int   u32;
typedef unsigned short u16;
typedef float f32x4  __attribute__((ext_vector_type(4)));
typedef short bf16x8 __attribute__((ext_vector_type(8)));

// ---------- bf16 helpers ----------
__device__ __forceinline__ float bf1(u16 u)  { return __uint_as_float(((u32)u) << 16); }
__device__ __forceinline__ float bflo(u32 u) { return __uint_as_float(u << 16); }
__device__ __forceinline__ float bfhi(u32 u) { return __uint_as_float(u & 0xffff0000u); }
__device__ __forceinline__ u16 f2bf(float f) {
    u32 x = __float_as_uint(f);
    u32 r = x + 0x7fffu + ((x >> 16) & 1u);   // RNE
    return (u16)(r >> 16);
}
__device__ __forceinline__ u32 pack2(float a, float b) {
    return (u32)f2bf(a) | ((u32)f2bf(b) << 16);
}

// ---------- dtype conversion ----------
__global__ __launch_bounds__(256) void cvt_x(const float2* __restrict__ x,
                                             u32* __restrict__ xbf) {
    int i = blockIdx.x * 256 + threadIdx.x;
    if (i < N_NODES * 64) { float2 v = x[i]; xbf[i] = pack2(v.x, v.y); }
}

// W: [L][128 k][128 n] fp32 -> Wt: [L][128 n][128 k] bf16; z selects W1/W2
__global__ __launch_bounds__(128) void cvt_w(const float* __restrict__ W1,
                                             const float* __restrict__ W2,
                                             short* __restrict__ W1t,
                                             short* __restrict__ W2t) {
    int l = blockIdx.y, n = blockIdx.x, k = threadIdx.x;
    const float* W = blockIdx.z ? W2 : W1;
    short* Wt      = blockIdx.z ? W2t : W1t;
    Wt[((size_t)l * 128 + n) * 128 + k] = (short)f2bf(W[((size_t)l * 128 + k) * 128 + n]);
}

// ---------- CSR build ----------
__global__ void count_deg(const int* __restrict__ dst, int* __restrict__ deg) {
    int e = blockIdx.x * 256 + threadIdx.x;
    if (e < N_EDGES) atomicAdd(&deg[dst[e]], 1);
}

__global__ __launch_bounds__(256) void scan_l1(const int* __restrict__ deg,
                                               int* __restrict__ bscan,
                                               int* __restrict__ bsum) {
    __shared__ int sd[256];
    int tid = threadIdx.x;
    int i = blockIdx.x * 256 + tid;
    int v = (i < N_NODES) ? deg[i] : 0;
    sd[tid] = v; __syncthreads();
#pragma unroll
    for (int off = 1; off < 256; off <<= 1) {
        int t = (tid >= off) ? sd[tid - off] : 0;
        __syncthreads();
        sd[tid] += t; __syncthreads();
    }
    if (i < N_NODES) bscan[i] = sd[tid];
    if (tid == 255) bsum[blockIdx.x] = sd[255];
}

__global__ __launch_bounds__(256) void scan_l2(const int* __restrict__ bsum,
                                               int* __restrict__ boff) {
    __shared__ int sd[256];
    int tid = threadIdx.x;
    int v = (tid < SCAN_NB) ? bsum[tid] : 0;
    sd[tid] = v; __syncthreads();
#pragma unroll
    for (int off = 1; off < 256; off <<= 1) {
        int t = (tid >= off) ? sd[tid - off] : 0;
        __syncthreads();
        sd[tid] += t; __syncthreads();
    }
    if (tid < SCAN_NB) boff[tid] = sd[tid] - v;
}

__global__ __launch_bounds__(256) void scan_l3(const int* __restrict__ bscan,
                                               const int* __restrict__ boff,
                                               int* __restrict__ rowp) {
    int i = blockIdx.x * 256 + threadIdx.x;
    if (i == 0) rowp[0] = 0;
    if (i < N_NODES) rowp[i + 1] = bscan[i] + boff[blockIdx.x];
}

__global__ void fill_csr(const int* __restrict__ src, const int* __restrict__ dst,
                         const int* __restrict__ rowp, int* __restrict__ cursor,
                         int* __restrict__ col) {
    int e = blockIdx.x * 256 + threadIdx.x;
    if (e < N_EDGES) {
        int d = dst[e];
        int pos = atomicAdd(&cursor[d], 1);
        col[rowp[d] + pos] = src[e];
    }
}

// ---------- GIN aggregation (bf16, fp32 accum, analytic BN of prev layer) ----------
// one wave per node; HALF-WAVE edge pairing: lanes 0-31 load edge 2t's row,
// lanes 32-63 load edge 2t+1's row (8 B/lane) -> one load instruction covers
// 2 edges; 8 loads in flight cover 16 edges (mean degree 12 -> 1 latency round).
__global__ __launch_bounds__(256) void agg_kernel(
    const u32* __restrict__ xin, const float* __restrict__ coef,
    const int* __restrict__ rowp, const int* __restrict__ col,
    const float* __restrict__ eps_all, int layer,
    u32* __restrict__ agg) {
    int node = blockIdx.x * 4 + (threadIdx.x >> 6);
    int lane = threadIdx.x & 63;
    if (node >= N_NODES) return;
    int sub  = lane & 31;   // u32-pair index within row (4 bf16 cols: 4*sub..4*sub+3)
    int half = lane >> 5;   // which edge of the pair this lane gathers
    float a[4], d[4];
    if (coef) {
#pragma unroll
        for (int c = 0; c < 4; c++) { a[c] = coef[4 * sub + c]; d[c] = coef[128 + 4 * sub + c]; }
    } else {
#pragma unroll
        for (int c = 0; c < 4; c++) { a[c] = 1.f; d[c] = 0.f; }
    }
    float ep = 1.0f + eps_all[layer];
    uint2 vv = *(const uint2*)(xin + (size_t)node * 64 + sub * 2);
    int k0 = rowp[node], k1 = rowp[node + 1];
    float s[4] = {0.f, 0.f, 0.f, 0.f};
    int k = k0;
    int cc[16];
    if (k < k1) {
#pragma unroll
        for (int t = 0; t < 16; t++) cc[t] = col[min(k + t, k1 - 1)];
    }
    while (k < k1) {
        int idx[8]; float w[8];
#pragma unroll
        for (int t = 0; t < 8; t++) {
            idx[t] = half ? cc[2 * t + 1] : cc[2 * t];
            w[t]   = (k + 2 * t + half < k1) ? 1.f : 0.f;
        }
        int kn = k + 16;
        if (kn < k1) {
#pragma unroll
            for (int t = 0; t < 16; t++) cc[t] = col[min(kn + t, k1 - 1)];
        }
#pragma unroll
        for (int t = 0; t < 8; t++) {
            uint2 u = *(const uint2*)(xin + (size_t)idx[t] * 64 + sub * 2);
            s[0] += w[t] * bflo(u.x); s[1] += w[t] * bfhi(u.x);
            s[2] += w[t] * bflo(u.y); s[3] += w[t] * bfhi(u.y);
        }
        k = kn;
    }
    // combine the two half-wave partials (same columns, different edge subsets)
#pragma unroll
    for (int c = 0; c < 4; c++) s[c] += __shfl_xor(s[c], 32, 64);
    if (half == 0) {
        float deg = (float)(k1 - k0);
        float x0 = bflo(vv.x), x1 = bfhi(vv.x), x2 = bflo(vv.y), x3 = bfhi(vv.y);
        float r0 = ep * (a[0] * x0 + d[0]) + a[0] * s[0] + deg * d[0];
        float r1 = ep * (a[1] * x1 + d[1]) + a[1] * s[1] + deg * d[1];
        float r2 = ep * (a[2] * x2 + d[2]) + a[2] * s[2] + deg * d[2];
        float r3 = ep * (a[3] * x3 + d[3]) + a[3] * s[3] + deg * d[3];
        uint2 o; o.x = pack2(r0, r1); o.y = pack2(r2, r3);
        *(uint2*)(agg + (size_t)node * 64 + sub * 2) = o;
    }
}

// ---------- fused MLP + BN-stats + per-graph pooling (round-10 proven config) ----------
#define H1_STRIDE 136
__global__ __launch_bounds__(256) void mlp_fused(
    const short* __restrict__ A,
    const short* __restrict__ W1t, const float* __restrict__ b1,
    const short* __restrict__ W2t, const float* __restrict__ b2,
    short* __restrict__ H2, const int* __restrict__ batch,
    float* __restrict__ partial, float* __restrict__ gsum, int M) {
    __shared__ alignas(16) short h1s[128 * H1_STRIDE];   // 34816 B, reused as scratch
    __shared__ int sh_ga, sh_gb, sh_split;
    int tid  = threadIdx.x;
    int wave = tid >> 6, lane = tid & 63;
    int ln15 = lane & 15, quad = lane >> 4;
    int m0blk = blockIdx.x * 128;
    int m0 = m0blk + wave * 32;
    const bf16x8 zz = {0, 0, 0, 0, 0, 0, 0, 0};

    if (tid == 0) {
        int rlo = m0blk, rhi = min(m0blk + 127, M - 1);
        int ga = batch[rlo], gb = batch[rhi];
        int split = m0blk + 128;
        if (ga != gb) {
            int lo = rlo, hi = rhi;
            while (lo + 1 < hi) { int mid = (lo + hi) >> 1; if (batch[mid] == ga) lo = mid; else hi = mid; }
            split = hi;
        }
        sh_ga = ga; sh_gb = gb; sh_split = split;
    }

    bf16x8 a[2][4];
#pragma unroll
    for (int rt = 0; rt < 2; rt++) {
        int row = m0 + rt * 16 + ln15;
        const short* rp = A + (size_t)row * 128 + quad * 8;
        bool ok = row < M;
#pragma unroll
        for (int s = 0; s < 4; s++)
            a[rt][s] = ok ? *(const bf16x8*)(rp + s * 32) : zz;
    }
#pragma unroll
    for (int ct = 0; ct < 8; ct++) {
        const short* wp = W1t + (size_t)(ct * 16 + ln15) * 128 + quad * 8;
        bf16x8 b[4];
#pragma unroll
        for (int s = 0; s < 4; s++) b[s] = *(const bf16x8*)(wp + s * 32);
        float bias = b1[ct * 16 + ln15];
#pragma unroll
        for (int rt = 0; rt < 2; rt++) {
            f32x4 acc = {0.f, 0.f, 0.f, 0.f};
#pragma unroll
            for (int s = 0; s < 4; s++)
                acc = __builtin_amdgcn_mfma_f32_16x16x32_bf16(a[rt][s], b[s], acc, 0, 0, 0);
#pragma unroll
            for (int i = 0; i < 4; i++) {
                float v = fmaxf(acc[i] + bias, 0.f);
                int lr = wave * 32 + rt * 16 + quad * 4 + i;
                h1s[lr * H1_STRIDE + ct * 16 + ln15] = (short)f2bf(v);
            }
        }
    }
    __syncthreads();
    bf16x8 c[2][4];
#pragma unroll
    for (int rt = 0; rt < 2; rt++) {
        const short* rp = h1s + (size_t)(wave * 32 + rt * 16 + ln15) * H1_STRIDE + quad * 8;
#pragma unroll
        for (int s = 0; s < 4; s++) c[rt][s] = *(const bf16x8*)(rp + s * 32);
    }
    int gsplit = sh_split;
    float sAcc[8], qAcc[8], pAcc[8];
#pragma unroll
    for (int ct = 0; ct < 8; ct++) { sAcc[ct] = 0.f; qAcc[ct] = 0.f; pAcc[ct] = 0.f; }
#pragma unroll
    for (int ct = 0; ct < 8; ct++) {
        const short* wp = W2t + (size_t)(ct * 16 + ln15) * 128 + quad * 8;
        bf16x8 b[4];
#pragma unroll
        for (int s = 0; s < 4; s++) b[s] = *(const bf16x8*)(wp + s * 32);
        float bias = b2[ct * 16 + ln15];
#pragma unroll
        for (int rt = 0; rt < 2; rt++) {
            f32x4 acc = {0.f, 0.f, 0.f, 0.f};
#pragma unroll
            for (int s = 0; s < 4; s++)
                acc = __builtin_amdgcn_mfma_f32_16x16x32_bf16(c[rt][s], b[s], acc, 0, 0, 0);
            int colx = ct * 16 + ln15;
#pragma unroll
            for (int i = 0; i < 4; i++) {
                int row = m0 + rt * 16 + quad * 4 + i;
                float v = fmaxf(acc[i] + bias, 0.f);
                if (row < M) H2[(size_t)row * 128 + colx] = (short)f2bf(v);
                float vm = (row < M) ? v : 0.f;
                sAcc[ct] += vm; qAcc[ct] += vm * vm;
                if (row < gsplit) pAcc[ct] += vm;
            }
        }
    }
    __syncthreads();
    float* scr = (float*)h1s;          // [3][16][128]
    int slice = wave * 4 + quad;
#pragma unroll
    for (int ct = 0; ct < 8; ct++) {
        int colx = ct * 16 + ln15;
        scr[(0 * 16 + slice) * 128 + colx] = sAcc[ct];
        scr[(1 * 16 + slice) * 128 + colx] = qAcc[ct];
        scr[(2 * 16 + slice) * 128 + colx] = pAcc[ct];
    }
    __syncthreads();
    if (tid < 128) {
        float ss = 0.f, qq = 0.f, pa = 0.f;
#pragma unroll
        for (int sl = 0; sl < 16; sl++) {
            ss += scr[(0 * 16 + sl) * 128 + tid];
            qq += scr[(1 * 16 + sl) * 128 + tid];
            pa += scr[(2 * 16 + sl) * 128 + tid];
        }
        partial[(size_t)blockIdx.x * 256 + tid]       = ss;
        partial[(size_t)blockIdx.x * 256 + 128 + tid] = qq;
        int ga = sh_ga, gb = sh_gb;
        atomicAdd(&gsum[ga * 128 + tid], pa);
        if (gb != ga) atomicAdd(&gsum[gb * 128 + tid], ss - pa);
    }
}

// ---------- fold block partials into sums ----------
__global__ __launch_bounds__(256) void reduce_partials(
    const float* __restrict__ partial, float* __restrict__ sums) {
    int t = threadIdx.x;
    int b0 = blockIdx.x * 13, b1 = min(b0 + 13, NBLK_MLP);
    if (b0 >= NBLK_MLP) return;
    float acc = 0.f;
    for (int b = b0; b < b1; b++) acc += partial[(size_t)b * 256 + t];
    atomicAdd(&sums[t], acc);
}

__global__ void bn_finalize(const float* __restrict__ sums,
                            const float* __restrict__ gamma, const float* __restrict__ beta,
                            int layer, float* __restrict__ coef) {
    int c = threadIdx.x;  // 128
    float mean = sums[c] / (float)N_NODES;
    float var  = sums[128 + c] / (float)N_NODES - mean * mean;
    float istd = rsqrtf(var + 1e-5f);
    float a = istd * gamma[layer * 128 + c];
    coef[c]       = a;
    coef[128 + c] = beta[layer * 128 + c] - mean * a;
}

// ---------- head: one block per graph, latency-pipelined dot loops ----------
__global__ __launch_bounds__(256) void head_kernel(
    const float* __restrict__ gsum, const float* __restrict__ coefL,
    const int* __restrict__ batch, const float* __restrict__ emb,
    const float* __restrict__ l1w, const float* __restrict__ l1b,
    const float* __restrict__ l2w, const float* __restrict__ l2b,
    const float* __restrict__ l4w, const float* __restrict__ l4b,
    float* __restrict__ out) {
    __shared__ float z[576];
    __shared__ float z1[256];
    __shared__ float z2h[2][128];
    __shared__ float z2[128];
    __shared__ float zr[128][10];
    __shared__ float inv_cnt;
    int g = blockIdx.x;
    int tid = threadIdx.x;
    if (tid == 0) {
        int lo = 0, hi = N_NODES;
        while (lo < hi) { int m = (lo + hi) >> 1; if (batch[m] < g) lo = m + 1; else hi = m; }
        int s = lo;
        lo = 0; hi = N_NODES;
        while (lo < hi) { int m = (lo + hi) >> 1; if (batch[m] < g + 1) lo = m + 1; else hi = m; }
        inv_cnt = 1.0f / fmaxf((float)(lo - s), 1.0f);
    }
    __syncthreads();
    for (int j = tid; j < 512; j += 256) {
        int l = j >> 7, c = j & 127;
        float a = coefL[l * 256 + c], d = coefL[l * 256 + 128 + c];
        z[j] = a * gsum[(size_t)l * NGRAPH * 128 + g * 128 + c] * inv_cnt + d;
    }
    if (tid < 64) z[512 + tid] = emb[g * 64 + tid];
    __syncthreads();
    {   // z1[256] = relu(z[576] @ l1w + b), 16-wide batched loads
        float acc = l1b[tid];
        for (int j0 = 0; j0 < 576; j0 += 16) {
            float lw[16];
#pragma unroll
            for (int t = 0; t < 16; t++) lw[t] = l1w[(j0 + t) * 256 + tid];
#pragma unroll
            for (int t = 0; t < 16; t++) acc += z[j0 + t] * lw[t];
        }
        z1[tid] = fmaxf(acc, 0.f);
    }
    __syncthreads();
    {   // z2[128] = relu(z1[256] @ l2w + b), split-K over 2 halves
        int c2 = tid & 127, half = tid >> 7;
        float acc = 0.f;
        int jb = half * 128;
        for (int j0 = 0; j0 < 128; j0 += 8) {
            float lw[8];
#pragma unroll
            for (int t = 0; t < 8; t++) lw[t] = l2w[(jb + j0 + t) * 128 + c2];
#pragma unroll
            for (int t = 0; t < 8; t++) acc += z1[jb + j0 + t] * lw[t];
        }
        z2h[half][c2] = acc;
    }
    __syncthreads();
    if (tid < 128) z2[tid] = fmaxf(z2h[0][tid] + z2h[1][tid] + l2b[tid], 0.f);
    __syncthreads();
    if (tid < 128) {
        float zv = z2[tid];
        const float* wr = l4w + tid * 10;
#pragma unroll
        for (int c = 0; c < 10; c++) zr[tid][c] = zv * wr[c];
    }
    __syncthreads();
    for (int s = 64; s >= 1; s >>= 1) {
        if (tid < s) {
#pragma unroll
            for (int c = 0; c < 10; c++) zr[tid][c] += zr[tid + s][c];
        }
        __syncthreads();
    }
    if (tid == 0) {
        float z3s[10];
#pragma unroll
        for (int c = 0; c < 10; c++) z3s[c] = zr[0][c] + l4b[c];
        float m = z3s[0];
        for (int i = 1; i < 10; i++) m = fmaxf(m, z3s[i]);
        float se = 0.f;
        for (int i = 0; i < 10; i++) se += expf(z3s[i] - m);
        float lse = m + logf(se);
        for (int i = 0; i < 10; i++) out[g * 10 + i] = z3s[i] - lse;
    }
}

extern "C" void kernel_launch(void* const* d_in, const int* in_sizes, int n_in,
                              void* d_out, int out_size, void* d_ws, size_t ws_size,
                              hipStream_t stream) {
    (void)in_sizes; (void)n_in; (void)out_size; (void)ws_size;
    const float* x0   = (const float*)d_in[0];
    const int* ei     = (const int*)d_in[1];
    const int* src    = ei;
    const int* dst    = ei + N_EDGES;
    const int* batch  = (const int*)d_in[2];
    const float* emb  = (const float*)d_in[3];
    const float* eps  = (const float*)d_in[4];
    const float* W1   = (const float*)d_in[5];
    const float* b1   = (const float*)d_in[6];
    const float* W2   = (const float*)d_in[7];
    const float* b2   = (const float*)d_in[8];
    const float* gamma= (const float*)d_in[9];
    const float* beta = (const float*)d_in[10];
    const float* l1w  = (const float*)d_in[11];
    const float* l1b  = (const float*)d_in[12];
    const float* l2w  = (const float*)d_in[13];
    const float* l2b  = (const float*)d_in[14];
    const float* l4w  = (const float*)d_in[15];
    const float* l4b  = (const float*)d_in[16];

    char* ws = (char*)d_ws;
    size_t off = 0;
    auto alloc = [&](size_t bytes) -> char* {
        char* p = ws + off; off += (bytes + 255) & ~(size_t)255; return p;
    };
    // single zero region: deg + cursor + sumsL + gsumL (contiguous)
    int* deg    = (int*)alloc(N_NODES * 4);
    int* cursor = (int*)alloc(N_NODES * 4);
    float* sumsL = (float*)alloc(NLAYER * 256 * 4);
    float* gsumL = (float*)alloc((size_t)NLAYER * NGRAPH * 128 * 4);
    size_t zero_len = (char*)gsumL - (char*)deg + (size_t)NLAYER * NGRAPH * 128 * 4;
    int* rowp   = (int*)alloc((N_NODES + 1) * 4);
    int* bscan  = (int*)alloc(N_NODES * 4);
    int* bsum   = (int*)alloc(SCAN_NB * 4);
    int* boff   = (int*)alloc(SCAN_NB * 4);
    int* col    = (int*)alloc(N_EDGES * 4);
    u32* xbf    = (u32*)alloc((size_t)N_NODES * 64 * 4);
    u32* agg    = (u32*)alloc((size_t)N_NODES * 64 * 4);
    u32* h2a    = (u32*)alloc((size_t)N_NODES * 64 * 4);
    u32* h2b    = (u32*)alloc((size_t)N_NODES * 64 * 4);
    short* W1t  = (short*)alloc((size_t)NLAYER * 128 * 128 * 2);
    short* W2t  = (short*)alloc((size_t)NLAYER * 128 * 128 * 2);
    float* partial = (float*)alloc((size_t)NBLK_MLP * 256 * 4);
    float* coefL = (float*)alloc(NLAYER * 256 * 4);

    hipMemsetAsync(deg, 0, zero_len, stream);

    cvt_x<<<(N_NODES * 64 + 255) / 256, 256, 0, stream>>>((const float2*)x0, xbf);
    {
        dim3 gw(128, NLAYER, 2);
        cvt_w<<<gw, 128, 0, stream>>>(W1, W2, W1t, W2t);
    }
    count_deg<<<(N_EDGES + 255) / 256, 256, 0, stream>>>(dst, deg);
    scan_l1<<<SCAN_NB, 256, 0, stream>>>(deg, bscan, bsum);
    scan_l2<<<1, 256, 0, stream>>>(bsum, boff);
    scan_l3<<<SCAN_NB, 256, 0, stream>>>(bscan, boff, rowp);
    fill_csr<<<(N_EDGES + 255) / 256, 256, 0, stream>>>(src, dst, rowp, cursor, col);

    const u32* xin = xbf;
    for (int l = 0; l < NLAYER; ++l) {
        u32* h2 = (l & 1) ? h2b : h2a;
        const float* coef_prev = (l == 0) ? nullptr : (coefL + (l - 1) * 256);
        agg_kernel<<<(N_NODES + 3) / 4, 256, 0, stream>>>(
            xin, coef_prev, rowp, col, eps, l, agg);
        mlp_fused<<<NBLK_MLP, 256, 0, stream>>>(
            (const short*)agg, W1t + (size_t)l * 16384, b1 + l * 128,
            W2t + (size_t)l * 16384, b2 + l * 128, (short*)h2, batch,
            partial, gsumL + (size_t)l * NGRAPH * 128, N_NODES);
        reduce_partials<<<RED_B, 256, 0, stream>>>(partial, sumsL + l * 256);
        bn_finalize<<<1, 128, 0, stream>>>(sumsL + l * 256, gamma, beta, l,
                                           coefL + l * 256);
        xin = h2;
    }
    head_kernel<<<NGRAPH, 256, 0, stream>>>(gsumL, coefL, batch, emb,
                                            l1w, l1b, l2w, l2b, l4w, l4b,
                                            (float*)d_out);
}

// Round 13
// 417.096 us; speedup vs baseline: 1.2791x; 1.2791x over previous
//
#include <hip/hip_runtime.h>
#include <cstdint>
#include <cstddef>

#define N_NODES 50000
#define N_EDGES 600000
#define NLAYER  4
#define NGRAPH  64
#define SCAN_NB 196   // ceil(50000/256)
#define NBLK_MLP ((N_NODES + 127) / 128)   // 391, 128-row MLP tiles
#define RED_B    ((NBLK_MLP + 12) / 13)    // 31 reduce blocks x 13 partials

typedef unsigned int   u32;
typedef unsigned short u16;
typedef float f32x4  __attribute__((ext_vector_type(4)));
typedef short bf16x8 __attribute__((ext_vector_type(8)));

// ---------- bf16 helpers ----------
__device__ __forceinline__ float bf1(u16 u)  { return __uint_as_float(((u32)u) << 16); }
__device__ __forceinline__ float bflo(u32 u) { return __uint_as_float(u << 16); }
__device__ __forceinline__ float bfhi(u32 u) { return __uint_as_float(u & 0xffff0000u); }
__device__ __forceinline__ u16 f2bf(float f) {
    u32 x = __float_as_uint(f);
    u32 r = x + 0x7fffu + ((x >> 16) & 1u);   // RNE
    return (u16)(r >> 16);
}
__device__ __forceinline__ u32 pack2(float a, float b) {
    return (u32)f2bf(a) | ((u32)f2bf(b) << 16);
}

// ---------- dtype conversion ----------
__global__ __launch_bounds__(256) void cvt_x(const float2* __restrict__ x,
                                             u32* __restrict__ xbf) {
    int i = blockIdx.x * 256 + threadIdx.x;
    if (i < N_NODES * 64) { float2 v = x[i]; xbf[i] = pack2(v.x, v.y); }
}

// W: [L][128 k][128 n] fp32 -> Wt: [L][128 n][128 k] bf16; z selects W1/W2
__global__ __launch_bounds__(128) void cvt_w(const float* __restrict__ W1,
                                             const float* __restrict__ W2,
                                             short* __restrict__ W1t,
                                             short* __restrict__ W2t) {
    int l = blockIdx.y, n = blockIdx.x, k = threadIdx.x;
    const float* W = blockIdx.z ? W2 : W1;
    short* Wt      = blockIdx.z ? W2t : W1t;
    Wt[((size_t)l * 128 + n) * 128 + k] = (short)f2bf(W[((size_t)l * 128 + k) * 128 + n]);
}

// ---------- CSR build ----------
__global__ void count_deg(const int* __restrict__ dst, int* __restrict__ deg) {
    int e = blockIdx.x * 256 + threadIdx.x;
    if (e < N_EDGES) atomicAdd(&deg[dst[e]], 1);
}

__global__ __launch_bounds__(256) void scan_l1(const int* __restrict__ deg,
                                               int* __restrict__ bscan,
                                               int* __restrict__ bsum) {
    __shared__ int sd[256];
    int tid = threadIdx.x;
    int i = blockIdx.x * 256 + tid;
    int v = (i < N_NODES) ? deg[i] : 0;
    sd[tid] = v; __syncthreads();
#pragma unroll
    for (int off = 1; off < 256; off <<= 1) {
        int t = (tid >= off) ? sd[tid - off] : 0;
        __syncthreads();
        sd[tid] += t; __syncthreads();
    }
    if (i < N_NODES) bscan[i] = sd[tid];
    if (tid == 255) bsum[blockIdx.x] = sd[255];
}

__global__ __launch_bounds__(256) void scan_l2(const int* __restrict__ bsum,
                                               int* __restrict__ boff) {
    __shared__ int sd[256];
    int tid = threadIdx.x;
    int v = (tid < SCAN_NB) ? bsum[tid] : 0;
    sd[tid] = v; __syncthreads();
#pragma unroll
    for (int off = 1; off < 256; off <<= 1) {
        int t = (tid >= off) ? sd[tid - off] : 0;
        __syncthreads();
        sd[tid] += t; __syncthreads();
    }
    if (tid < SCAN_NB) boff[tid] = sd[tid] - v;
}

__global__ __launch_bounds__(256) void scan_l3(const int* __restrict__ bscan,
                                               const int* __restrict__ boff,
                                               int* __restrict__ rowp) {
    int i = blockIdx.x * 256 + threadIdx.x;
    if (i == 0) rowp[0] = 0;
    if (i < N_NODES) rowp[i + 1] = bscan[i] + boff[blockIdx.x];
}

__global__ void fill_csr(const int* __restrict__ src, const int* __restrict__ dst,
                         const int* __restrict__ rowp, int* __restrict__ cursor,
                         int* __restrict__ col) {
    int e = blockIdx.x * 256 + threadIdx.x;
    if (e < N_EDGES) {
        int d = dst[e];
        int pos = atomicAdd(&cursor[d], 1);
        col[rowp[d] + pos] = src[e];
    }
}

// ---------- GIN aggregation (bf16, fp32 accum, analytic BN of prev layer) ----------
// one wave per node; 8-deep software-pipelined edge loop (round-10 proven config)
__global__ __launch_bounds__(256) void agg_kernel(
    const u32* __restrict__ xin, const float* __restrict__ coef,
    const int* __restrict__ rowp, const int* __restrict__ col,
    const float* __restrict__ eps_all, int layer,
    u32* __restrict__ agg) {
    int node = blockIdx.x * 4 + (threadIdx.x >> 6);
    int lane = threadIdx.x & 63;
    if (node >= N_NODES) return;
    float a0 = 1.f, a1 = 1.f, d0 = 0.f, d1 = 0.f;
    if (coef) {
        a0 = coef[2 * lane];       a1 = coef[2 * lane + 1];
        d0 = coef[128 + 2 * lane]; d1 = coef[128 + 2 * lane + 1];
    }
    float ep = 1.0f + eps_all[layer];
    u32 v = xin[(size_t)node * 64 + lane];
    int k0 = rowp[node], k1 = rowp[node + 1];
    float s0 = 0.f, s1 = 0.f;
    int k = k0;
    int cc[8];
    if (k < k1) {
#pragma unroll
        for (int t = 0; t < 8; t++) cc[t] = col[min(k + t, k1 - 1)];
    }
    while (k < k1) {
        int idx[8];
#pragma unroll
        for (int t = 0; t < 8; t++) idx[t] = cc[t];
        int kn = k + 8;
        if (kn < k1) {
#pragma unroll
            for (int t = 0; t < 8; t++) cc[t] = col[min(kn + t, k1 - 1)];
        }
#pragma unroll
        for (int t = 0; t < 8; t++) {
            u32 u = xin[(size_t)idx[t] * 64 + lane];
            float w = (k + t < k1) ? 1.f : 0.f;
            s0 += w * bflo(u); s1 += w * bfhi(u);
        }
        k = kn;
    }
    float deg = (float)(k1 - k0);
    float r0 = ep * (a0 * bflo(v) + d0) + a0 * s0 + deg * d0;
    float r1 = ep * (a1 * bfhi(v) + d1) + a1 * s1 + deg * d1;
    agg[(size_t)node * 64 + lane] = pack2(r0, r1);
}

// ---------- fused MLP + BN-stats + per-graph pooling (round-10 proven config) ----------
#define H1_STRIDE 136
__global__ __launch_bounds__(256) void mlp_fused(
    const short* __restrict__ A,
    const short* __restrict__ W1t, const float* __restrict__ b1,
    const short* __restrict__ W2t, const float* __restrict__ b2,
    short* __restrict__ H2, const int* __restrict__ batch,
    float* __restrict__ partial, float* __restrict__ gsum, int M) {
    __shared__ alignas(16) short h1s[128 * H1_STRIDE];   // 34816 B, reused as scratch
    __shared__ int sh_ga, sh_gb, sh_split;
    int tid  = threadIdx.x;
    int wave = tid >> 6, lane = tid & 63;
    int ln15 = lane & 15, quad = lane >> 4;
    int m0blk = blockIdx.x * 128;
    int m0 = m0blk + wave * 32;
    const bf16x8 zz = {0, 0, 0, 0, 0, 0, 0, 0};

    if (tid == 0) {
        int rlo = m0blk, rhi = min(m0blk + 127, M - 1);
        int ga = batch[rlo], gb = batch[rhi];
        int split = m0blk + 128;
        if (ga != gb) {
            int lo = rlo, hi = rhi;
            while (lo + 1 < hi) { int mid = (lo + hi) >> 1; if (batch[mid] == ga) lo = mid; else hi = mid; }
            split = hi;
        }
        sh_ga = ga; sh_gb = gb; sh_split = split;
    }

    bf16x8 a[2][4];
#pragma unroll
    for (int rt = 0; rt < 2; rt++) {
        int row = m0 + rt * 16 + ln15;
        const short* rp = A + (size_t)row * 128 + quad * 8;
        bool ok = row < M;
#pragma unroll
        for (int s = 0; s < 4; s++)
            a[rt][s] = ok ? *(const bf16x8*)(rp + s * 32) : zz;
    }
#pragma unroll
    for (int ct = 0; ct < 8; ct++) {
        const short* wp = W1t + (size_t)(ct * 16 + ln15) * 128 + quad * 8;
        bf16x8 b[4];
#pragma unroll
        for (int s = 0; s < 4; s++) b[s] = *(const bf16x8*)(wp + s * 32);
        float bias = b1[ct * 16 + ln15];
#pragma unroll
        for (int rt = 0; rt < 2; rt++) {
            f32x4 acc = {0.f, 0.f, 0.f, 0.f};
#pragma unroll
            for (int s = 0; s < 4; s++)
                acc = __builtin_amdgcn_mfma_f32_16x16x32_bf16(a[rt][s], b[s], acc, 0, 0, 0);
#pragma unroll
            for (int i = 0; i < 4; i++) {
                float v = fmaxf(acc[i] + bias, 0.f);
                int lr = wave * 32 + rt * 16 + quad * 4 + i;
                h1s[lr * H1_STRIDE + ct * 16 + ln15] = (short)f2bf(v);
            }
        }
    }
    __syncthreads();
    bf16x8 c[2][4];
#pragma unroll
    for (int rt = 0; rt < 2; rt++) {
        const short* rp = h1s + (size_t)(wave * 32 + rt * 16 + ln15) * H1_STRIDE + quad * 8;
#pragma unroll
        for (int s = 0; s < 4; s++) c[rt][s] = *(const bf16x8*)(rp + s * 32);
    }
    int gsplit = sh_split;
    float sAcc[8], qAcc[8], pAcc[8];
#pragma unroll
    for (int ct = 0; ct < 8; ct++) { sAcc[ct] = 0.f; qAcc[ct] = 0.f; pAcc[ct] = 0.f; }
#pragma unroll
    for (int ct = 0; ct < 8; ct++) {
        const short* wp = W2t + (size_t)(ct * 16 + ln15) * 128 + quad * 8;
        bf16x8 b[4];
#pragma unroll
        for (int s = 0; s < 4; s++) b[s] = *(const bf16x8*)(wp + s * 32);
        float bias = b2[ct * 16 + ln15];
#pragma unroll
        for (int rt = 0; rt < 2; rt++) {
            f32x4 acc = {0.f, 0.f, 0.f, 0.f};
#pragma unroll
            for (int s = 0; s < 4; s++)
                acc = __builtin_amdgcn_mfma_f32_16x16x32_bf16(c[rt][s], b[s], acc, 0, 0, 0);
            int colx = ct * 16 + ln15;
#pragma unroll
            for (int i = 0; i < 4; i++) {
                int row = m0 + rt * 16 + quad * 4 + i;
                float v = fmaxf(acc[i] + bias, 0.f);
                if (row < M) H2[(size_t)row * 128 + colx] = (short)f2bf(v);
                float vm = (row < M) ? v : 0.f;
                sAcc[ct] += vm; qAcc[ct] += vm * vm;
                if (row < gsplit) pAcc[ct] += vm;
            }
        }
    }
    __syncthreads();
    float* scr = (float*)h1s;          // [3][16][128]
    int slice = wave * 4 + quad;
#pragma unroll
    for (int ct = 0; ct < 8; ct++) {
        int colx = ct * 16 + ln15;
        scr[(0 * 16 + slice) * 128 + colx] = sAcc[ct];
        scr[(1 * 16 + slice) * 128 + colx] = qAcc[ct];
        scr[(2 * 16 + slice) * 128 + colx] = pAcc[ct];
    }
    __syncthreads();
    if (tid < 128) {
        float ss = 0.f, qq = 0.f, pa = 0.f;
#pragma unroll
        for (int sl = 0; sl < 16; sl++) {
            ss += scr[(0 * 16 + sl) * 128 + tid];
            qq += scr[(1 * 16 + sl) * 128 + tid];
            pa += scr[(2 * 16 + sl) * 128 + tid];
        }
        partial[(size_t)blockIdx.x * 256 + tid]       = ss;
        partial[(size_t)blockIdx.x * 256 + 128 + tid] = qq;
        int ga = sh_ga, gb = sh_gb;
        atomicAdd(&gsum[ga * 128 + tid], pa);
        if (gb != ga) atomicAdd(&gsum[gb * 128 + tid], ss - pa);
    }
}

// ---------- fold block partials into sums ----------
__global__ __launch_bounds__(256) void reduce_partials(
    const float* __restrict__ partial, float* __restrict__ sums) {
    int t = threadIdx.x;
    int b0 = blockIdx.x * 13, b1 = min(b0 + 13, NBLK_MLP);
    if (b0 >= NBLK_MLP) return;
    float acc = 0.f;
    for (int b = b0; b < b1; b++) acc += partial[(size_t)b * 256 + t];
    atomicAdd(&sums[t], acc);
}

__global__ void bn_finalize(const float* __restrict__ sums,
                            const float* __restrict__ gamma, const float* __restrict__ beta,
                            int layer, float* __restrict__ coef) {
    int c = threadIdx.x;  // 128
    float mean = sums[c] / (float)N_NODES;
    float var  = sums[128 + c] / (float)N_NODES - mean * mean;
    float istd = rsqrtf(var + 1e-5f);
    float a = istd * gamma[layer * 128 + c];
    coef[c]       = a;
    coef[128 + c] = beta[layer * 128 + c] - mean * a;
}

// ---------- head: one block per graph, latency-pipelined dot loops ----------
__global__ __launch_bounds__(256) void head_kernel(
    const float* __restrict__ gsum, const float* __restrict__ coefL,
    const int* __restrict__ batch, const float* __restrict__ emb,
    const float* __restrict__ l1w, const float* __restrict__ l1b,
    const float* __restrict__ l2w, const float* __restrict__ l2b,
    const float* __restrict__ l4w, const float* __restrict__ l4b,
    float* __restrict__ out) {
    __shared__ float z[576];
    __shared__ float z1[256];
    __shared__ float z2h[2][128];
    __shared__ float z2[128];
    __shared__ float zr[128][10];
    __shared__ float inv_cnt;
    int g = blockIdx.x;
    int tid = threadIdx.x;
    if (tid == 0) {
        int lo = 0, hi = N_NODES;
        while (lo < hi) { int m = (lo + hi) >> 1; if (batch[m] < g) lo = m + 1; else hi = m; }
        int s = lo;
        lo = 0; hi = N_NODES;
        while (lo < hi) { int m = (lo + hi) >> 1; if (batch[m] < g + 1) lo = m + 1; else hi = m; }
        inv_cnt = 1.0f / fmaxf((float)(lo - s), 1.0f);
    }
    __syncthreads();
    for (int j = tid; j < 512; j += 256) {
        int l = j >> 7, c = j & 127;
        float a = coefL[l * 256 + c], d = coefL[l * 256 + 128 + c];
        z[j] = a * gsum[(size_t)l * NGRAPH * 128 + g * 128 + c] * inv_cnt + d;
    }
    if (tid < 64) z[512 + tid] = emb[g * 64 + tid];
    __syncthreads();
    {   // z1[256] = relu(z[576] @ l1w + b), 16-wide batched loads
        float acc = l1b[tid];
        for (int j0 = 0; j0 < 576; j0 += 16) {
            float lw[16];
#pragma unroll
            for (int t = 0; t < 16; t++) lw[t] = l1w[(j0 + t) * 256 + tid];
#pragma unroll
            for (int t = 0; t < 16; t++) acc += z[j0 + t] * lw[t];
        }
        z1[tid] = fmaxf(acc, 0.f);
    }
    __syncthreads();
    {   // z2[128] = relu(z1[256] @ l2w + b), split-K over 2 halves
        int c2 = tid & 127, half = tid >> 7;
        float acc = 0.f;
        int jb = half * 128;
        for (int j0 = 0; j0 < 128; j0 += 8) {
            float lw[8];
#pragma unroll
            for (int t = 0; t < 8; t++) lw[t] = l2w[(jb + j0 + t) * 128 + c2];
#pragma unroll
            for (int t = 0; t < 8; t++) acc += z1[jb + j0 + t] * lw[t];
        }
        z2h[half][c2] = acc;
    }
    __syncthreads();
    if (tid < 128) z2[tid] = fmaxf(z2h[0][tid] + z2h[1][tid] + l2b[tid], 0.f);
    __syncthreads();
    if (tid < 128) {
        float zv = z2[tid];
        const float* wr = l4w + tid * 10;
#pragma unroll
        for (int c = 0; c < 10; c++) zr[tid][c] = zv * wr[c];
    }
    __syncthreads();
    for (int s = 64; s >= 1; s >>= 1) {
        if (tid < s) {
#pragma unroll
            for (int c = 0; c < 10; c++) zr[tid][c] += zr[tid + s][c];
        }
        __syncthreads();
    }
    if (tid == 0) {
        float z3s[10];
#pragma unroll
        for (int c = 0; c < 10; c++) z3s[c] = zr[0][c] + l4b[c];
        float m = z3s[0];
        for (int i = 1; i < 10; i++) m = fmaxf(m, z3s[i]);
        float se = 0.f;
        for (int i = 0; i < 10; i++) se += expf(z3s[i] - m);
        float lse = m + logf(se);
        for (int i = 0; i < 10; i++) out[g * 10 + i] = z3s[i] - lse;
    }
}

extern "C" void kernel_launch(void* const* d_in, const int* in_sizes, int n_in,
                              void* d_out, int out_size, void* d_ws, size_t ws_size,
                              hipStream_t stream) {
    (void)in_sizes; (void)n_in; (void)out_size; (void)ws_size;
    const float* x0   = (const float*)d_in[0];
    const int* ei     = (const int*)d_in[1];
    const int* src    = ei;
    const int* dst    = ei + N_EDGES;
    const int* batch  = (const int*)d_in[2];
    const float* emb  = (const float*)d_in[3];
    const float* eps  = (const float*)d_in[4];
    const float* W1   = (const float*)d_in[5];
    const float* b1   = (const float*)d_in[6];
    const float* W2   = (const float*)d_in[7];
    const float* b2   = (const float*)d_in[8];
    const float* gamma= (const float*)d_in[9];
    const float* beta = (const float*)d_in[10];
    const float* l1w  = (const float*)d_in[11];
    const float* l1b  = (const float*)d_in[12];
    const float* l2w  = (const float*)d_in[13];
    const float* l2b  = (const float*)d_in[14];
    const float* l4w  = (const float*)d_in[15];
    const float* l4b  = (const float*)d_in[16];

    char* ws = (char*)d_ws;
    size_t off = 0;
    auto alloc = [&](size_t bytes) -> char* {
        char* p = ws + off; off += (bytes + 255) & ~(size_t)255; return p;
    };
    // single zero region: deg + cursor + sumsL + gsumL (contiguous)
    int* deg    = (int*)alloc(N_NODES * 4);
    int* cursor = (int*)alloc(N_NODES * 4);
    float* sumsL = (float*)alloc(NLAYER * 256 * 4);
    float* gsumL = (float*)alloc((size_t)NLAYER * NGRAPH * 128 * 4);
    size_t zero_len = (char*)gsumL - (char*)deg + (size_t)NLAYER * NGRAPH * 128 * 4;
    int* rowp   = (int*)alloc((N_NODES + 1) * 4);
    int* bscan  = (int*)alloc(N_NODES * 4);
    int* bsum   = (int*)alloc(SCAN_NB * 4);
    int* boff   = (int*)alloc(SCAN_NB * 4);
    int* col    = (int*)alloc(N_EDGES * 4);
    u32* xbf    = (u32*)alloc((size_t)N_NODES * 64 * 4);
    u32* agg    = (u32*)alloc((size_t)N_NODES * 64 * 4);
    u32* h2a    = (u32*)alloc((size_t)N_NODES * 64 * 4);
    u32* h2b    = (u32*)alloc((size_t)N_NODES * 64 * 4);
    short* W1t  = (short*)alloc((size_t)NLAYER * 128 * 128 * 2);
    short* W2t  = (short*)alloc((size_t)NLAYER * 128 * 128 * 2);
    float* partial = (float*)alloc((size_t)NBLK_MLP * 256 * 4);
    float* coefL = (float*)alloc(NLAYER * 256 * 4);

    hipMemsetAsync(deg, 0, zero_len, stream);

    cvt_x<<<(N_NODES * 64 + 255) / 256, 256, 0, stream>>>((const float2*)x0, xbf);
    {
        dim3 gw(128, NLAYER, 2);
        cvt_w<<<gw, 128, 0, stream>>>(W1, W2, W1t, W2t);
    }
    count_deg<<<(N_EDGES + 255) / 256, 256, 0, stream>>>(dst, deg);
    scan_l1<<<SCAN_NB, 256, 0, stream>>>(deg, bscan, bsum);
    scan_l2<<<1, 256, 0, stream>>>(bsum, boff);
    scan_l3<<<SCAN_NB, 256, 0, stream>>>(bscan, boff, rowp);
    fill_csr<<<(N_EDGES + 255) / 256, 256, 0, stream>>>(src, dst, rowp, cursor, col);

    const u32* xin = xbf;
    for (int l = 0; l < NLAYER; ++l) {
        u32* h2 = (l & 1) ? h2b : h2a;
        const float* coef_prev = (l == 0) ? nullptr : (coefL + (l - 1) * 256);
        agg_kernel<<<(N_NODES + 3) / 4, 256, 0, stream>>>(
            xin, coef_prev, rowp, col, eps, l, agg);
        mlp_fused<<<NBLK_MLP, 256, 0, stream>>>(
            (const short*)agg, W1t + (size_t)l * 16384, b1 + l * 128,
            W2t + (size_t)l * 16384, b2 + l * 128, (short*)h2, batch,
            partial, gsumL + (size_t)l * NGRAPH * 128, N_NODES);
        reduce_partials<<<RED_B, 256, 0, stream>>>(partial, sumsL + l * 256);
        bn_finalize<<<1, 128, 0, stream>>>(sumsL + l * 256, gamma, beta, l,
                                           coefL + l * 256);
        xin = h2;
    }
    head_kernel<<<NGRAPH, 256, 0, stream>>>(gsumL, coefL, batch, emb,
                                            l1w, l1b, l2w, l2b, l4w, l4b,
                                            (float*)d_out);
}

// Round 14
// 416.103 us; speedup vs baseline: 1.2821x; 1.0024x over previous
//
#include <hip/hip_runtime.h>
#include <cstdint>
#include <cstddef>

#define N_NODES 50000
#define N_EDGES 600000
#define NLAYER  4
#define NGRAPH  64
#define SCAN_NB 196   // ceil(50000/256)
#define NBLK_MLP ((N_NODES + 127) / 128)   // 391, 128-row MLP tiles
#define RED_B    ((NBLK_MLP + 12) / 13)    // 31 reduce blocks x 13 partials

typedef unsigned int   u32;
typedef unsigned short u16;
typedef float f32x4  __attribute__((ext_vector_type(4)));
typedef short bf16x8 __attribute__((ext_vector_type(8)));

// ---------- bf16 helpers ----------
__device__ __forceinline__ float bf1(u16 u)  { return __uint_as_float(((u32)u) << 16); }
__device__ __forceinline__ float bflo(u32 u) { return __uint_as_float(u << 16); }
__device__ __forceinline__ float bfhi(u32 u) { return __uint_as_float(u & 0xffff0000u); }
__device__ __forceinline__ u16 f2bf(float f) {
    u32 x = __float_as_uint(f);
    u32 r = x + 0x7fffu + ((x >> 16) & 1u);   // RNE
    return (u16)(r >> 16);
}
__device__ __forceinline__ u32 pack2(float a, float b) {
    return (u32)f2bf(a) | ((u32)f2bf(b) << 16);
}

// ---------- dtype conversion ----------
__global__ __launch_bounds__(256) void cvt_x(const float2* __restrict__ x,
                                             u32* __restrict__ xbf) {
    int i = blockIdx.x * 256 + threadIdx.x;
    if (i < N_NODES * 64) { float2 v = x[i]; xbf[i] = pack2(v.x, v.y); }
}

// W: [L][128 k][128 n] fp32 -> Wt: [L][128 n][128 k] bf16; z selects W1/W2
__global__ __launch_bounds__(128) void cvt_w(const float* __restrict__ W1,
                                             const float* __restrict__ W2,
                                             short* __restrict__ W1t,
                                             short* __restrict__ W2t) {
    int l = blockIdx.y, n = blockIdx.x, k = threadIdx.x;
    const float* W = blockIdx.z ? W2 : W1;
    short* Wt      = blockIdx.z ? W2t : W1t;
    Wt[((size_t)l * 128 + n) * 128 + k] = (short)f2bf(W[((size_t)l * 128 + k) * 128 + n]);
}

// ---------- CSR build ----------
__global__ void count_deg(const int* __restrict__ dst, int* __restrict__ deg) {
    int e = blockIdx.x * 256 + threadIdx.x;
    if (e < N_EDGES) atomicAdd(&deg[dst[e]], 1);
}

__global__ __launch_bounds__(256) void scan_l1(const int* __restrict__ deg,
                                               int* __restrict__ bscan,
                                               int* __restrict__ bsum) {
    __shared__ int sd[256];
    int tid = threadIdx.x;
    int i = blockIdx.x * 256 + tid;
    int v = (i < N_NODES) ? deg[i] : 0;
    sd[tid] = v; __syncthreads();
#pragma unroll
    for (int off = 1; off < 256; off <<= 1) {
        int t = (tid >= off) ? sd[tid - off] : 0;
        __syncthreads();
        sd[tid] += t; __syncthreads();
    }
    if (i < N_NODES) bscan[i] = sd[tid];
    if (tid == 255) bsum[blockIdx.x] = sd[255];
}

__global__ __launch_bounds__(256) void scan_l2(const int* __restrict__ bsum,
                                               int* __restrict__ boff) {
    __shared__ int sd[256];
    int tid = threadIdx.x;
    int v = (tid < SCAN_NB) ? bsum[tid] : 0;
    sd[tid] = v; __syncthreads();
#pragma unroll
    for (int off = 1; off < 256; off <<= 1) {
        int t = (tid >= off) ? sd[tid - off] : 0;
        __syncthreads();
        sd[tid] += t; __syncthreads();
    }
    if (tid < SCAN_NB) boff[tid] = sd[tid] - v;
}

__global__ __launch_bounds__(256) void scan_l3(const int* __restrict__ bscan,
                                               const int* __restrict__ boff,
                                               int* __restrict__ rowp) {
    int i = blockIdx.x * 256 + threadIdx.x;
    if (i == 0) rowp[0] = 0;
    if (i < N_NODES) rowp[i + 1] = bscan[i] + boff[blockIdx.x];
}

__global__ void fill_csr(const int* __restrict__ src, const int* __restrict__ dst,
                         const int* __restrict__ rowp, int* __restrict__ cursor,
                         int* __restrict__ col) {
    int e = blockIdx.x * 256 + threadIdx.x;
    if (e < N_EDGES) {
        int d = dst[e];
        int pos = atomicAdd(&cursor[d], 1);
        col[rowp[d] + pos] = src[e];
    }
}

// ---------- GIN aggregation (bf16, fp32 accum, analytic BN of prev layer) ----------
// one wave per node; 8-deep software-pipelined edge loop (round-10 proven config)
__global__ __launch_bounds__(256) void agg_kernel(
    const u32* __restrict__ xin, const float* __restrict__ coef,
    const int* __restrict__ rowp, const int* __restrict__ col,
    const float* __restrict__ eps_all, int layer,
    u32* __restrict__ agg) {
    int node = blockIdx.x * 4 + (threadIdx.x >> 6);
    int lane = threadIdx.x & 63;
    if (node >= N_NODES) return;
    float a0 = 1.f, a1 = 1.f, d0 = 0.f, d1 = 0.f;
    if (coef) {
        a0 = coef[2 * lane];       a1 = coef[2 * lane + 1];
        d0 = coef[128 + 2 * lane]; d1 = coef[128 + 2 * lane + 1];
    }
    float ep = 1.0f + eps_all[layer];
    u32 v = xin[(size_t)node * 64 + lane];
    int k0 = rowp[node], k1 = rowp[node + 1];
    float s0 = 0.f, s1 = 0.f;
    int k = k0;
    int cc[8];
    if (k < k1) {
#pragma unroll
        for (int t = 0; t < 8; t++) cc[t] = col[min(k + t, k1 - 1)];
    }
    while (k < k1) {
        int idx[8];
#pragma unroll
        for (int t = 0; t < 8; t++) idx[t] = cc[t];
        int kn = k + 8;
        if (kn < k1) {
#pragma unroll
            for (int t = 0; t < 8; t++) cc[t] = col[min(kn + t, k1 - 1)];
        }
#pragma unroll
        for (int t = 0; t < 8; t++) {
            u32 u = xin[(size_t)idx[t] * 64 + lane];
            float w = (k + t < k1) ? 1.f : 0.f;
            s0 += w * bflo(u); s1 += w * bfhi(u);
        }
        k = kn;
    }
    float deg = (float)(k1 - k0);
    float r0 = ep * (a0 * bflo(v) + d0) + a0 * s0 + deg * d0;
    float r1 = ep * (a1 * bfhi(v) + d1) + a1 * s1 + deg * d1;
    agg[(size_t)node * 64 + lane] = pack2(r0, r1);
}

// ---------- fused MLP + BN-stats + per-graph pooling (round-10 proven config) ----------
#define H1_STRIDE 136
__global__ __launch_bounds__(256) void mlp_fused(
    const short* __restrict__ A,
    const short* __restrict__ W1t, const float* __restrict__ b1,
    const short* __restrict__ W2t, const float* __restrict__ b2,
    short* __restrict__ H2, const int* __restrict__ batch,
    float* __restrict__ partial, float* __restrict__ gsum, int M) {
    __shared__ alignas(16) short h1s[128 * H1_STRIDE];   // 34816 B, reused as scratch
    __shared__ int sh_ga, sh_gb, sh_split;
    int tid  = threadIdx.x;
    int wave = tid >> 6, lane = tid & 63;
    int ln15 = lane & 15, quad = lane >> 4;
    int m0blk = blockIdx.x * 128;
    int m0 = m0blk + wave * 32;
    const bf16x8 zz = {0, 0, 0, 0, 0, 0, 0, 0};

    if (tid == 0) {
        int rlo = m0blk, rhi = min(m0blk + 127, M - 1);
        int ga = batch[rlo], gb = batch[rhi];
        int split = m0blk + 128;
        if (ga != gb) {
            int lo = rlo, hi = rhi;
            while (lo + 1 < hi) { int mid = (lo + hi) >> 1; if (batch[mid] == ga) lo = mid; else hi = mid; }
            split = hi;
        }
        sh_ga = ga; sh_gb = gb; sh_split = split;
    }

    bf16x8 a[2][4];
#pragma unroll
    for (int rt = 0; rt < 2; rt++) {
        int row = m0 + rt * 16 + ln15;
        const short* rp = A + (size_t)row * 128 + quad * 8;
        bool ok = row < M;
#pragma unroll
        for (int s = 0; s < 4; s++)
            a[rt][s] = ok ? *(const bf16x8*)(rp + s * 32) : zz;
    }
#pragma unroll
    for (int ct = 0; ct < 8; ct++) {
        const short* wp = W1t + (size_t)(ct * 16 + ln15) * 128 + quad * 8;
        bf16x8 b[4];
#pragma unroll
        for (int s = 0; s < 4; s++) b[s] = *(const bf16x8*)(wp + s * 32);
        float bias = b1[ct * 16 + ln15];
#pragma unroll
        for (int rt = 0; rt < 2; rt++) {
            f32x4 acc = {0.f, 0.f, 0.f, 0.f};
#pragma unroll
            for (int s = 0; s < 4; s++)
                acc = __builtin_amdgcn_mfma_f32_16x16x32_bf16(a[rt][s], b[s], acc, 0, 0, 0);
#pragma unroll
            for (int i = 0; i < 4; i++) {
                float v = fmaxf(acc[i] + bias, 0.f);
                int lr = wave * 32 + rt * 16 + quad * 4 + i;
                h1s[lr * H1_STRIDE + ct * 16 + ln15] = (short)f2bf(v);
            }
        }
    }
    __syncthreads();
    bf16x8 c[2][4];
#pragma unroll
    for (int rt = 0; rt < 2; rt++) {
        const short* rp = h1s + (size_t)(wave * 32 + rt * 16 + ln15) * H1_STRIDE + quad * 8;
#pragma unroll
        for (int s = 0; s < 4; s++) c[rt][s] = *(const bf16x8*)(rp + s * 32);
    }
    int gsplit = sh_split;
    float sAcc[8], qAcc[8], pAcc[8];
#pragma unroll
    for (int ct = 0; ct < 8; ct++) { sAcc[ct] = 0.f; qAcc[ct] = 0.f; pAcc[ct] = 0.f; }
#pragma unroll
    for (int ct = 0; ct < 8; ct++) {
        const short* wp = W2t + (size_t)(ct * 16 + ln15) * 128 + quad * 8;
        bf16x8 b[4];
#pragma unroll
        for (int s = 0; s < 4; s++) b[s] = *(const bf16x8*)(wp + s * 32);
        float bias = b2[ct * 16 + ln15];
#pragma unroll
        for (int rt = 0; rt < 2; rt++) {
            f32x4 acc = {0.f, 0.f, 0.f, 0.f};
#pragma unroll
            for (int s = 0; s < 4; s++)
                acc = __builtin_amdgcn_mfma_f32_16x16x32_bf16(c[rt][s], b[s], acc, 0, 0, 0);
            int colx = ct * 16 + ln15;
#pragma unroll
            for (int i = 0; i < 4; i++) {
                int row = m0 + rt * 16 + quad * 4 + i;
                float v = fmaxf(acc[i] + bias, 0.f);
                if (row < M) H2[(size_t)row * 128 + colx] = (short)f2bf(v);
                float vm = (row < M) ? v : 0.f;
                sAcc[ct] += vm; qAcc[ct] += vm * vm;
                if (row < gsplit) pAcc[ct] += vm;
            }
        }
    }
    __syncthreads();
    float* scr = (float*)h1s;          // [3][16][128]
    int slice = wave * 4 + quad;
#pragma unroll
    for (int ct = 0; ct < 8; ct++) {
        int colx = ct * 16 + ln15;
        scr[(0 * 16 + slice) * 128 + colx] = sAcc[ct];
        scr[(1 * 16 + slice) * 128 + colx] = qAcc[ct];
        scr[(2 * 16 + slice) * 128 + colx] = pAcc[ct];
    }
    __syncthreads();
    if (tid < 128) {
        float ss = 0.f, qq = 0.f, pa = 0.f;
#pragma unroll
        for (int sl = 0; sl < 16; sl++) {
            ss += scr[(0 * 16 + sl) * 128 + tid];
            qq += scr[(1 * 16 + sl) * 128 + tid];
            pa += scr[(2 * 16 + sl) * 128 + tid];
        }
        partial[(size_t)blockIdx.x * 256 + tid]       = ss;
        partial[(size_t)blockIdx.x * 256 + 128 + tid] = qq;
        int ga = sh_ga, gb = sh_gb;
        atomicAdd(&gsum[ga * 128 + tid], pa);
        if (gb != ga) atomicAdd(&gsum[gb * 128 + tid], ss - pa);
    }
}

// ---------- fold block partials into sums + last-block BN finalize ----------
__global__ __launch_bounds__(256) void reduce_finalize(
    const float* __restrict__ partial, float* __restrict__ sums,
    int* __restrict__ red_cnt,
    const float* __restrict__ gamma, const float* __restrict__ beta,
    int layer, float* __restrict__ coef) {
    int t = threadIdx.x;
    int b0 = blockIdx.x * 13, b1 = min(b0 + 13, NBLK_MLP);
    if (b0 < NBLK_MLP) {
        float acc = 0.f;
        for (int b = b0; b < b1; b++) acc += partial[(size_t)b * 256 + t];
        atomicAdd(&sums[t], acc);
    }
    __threadfence();   // release our sums contributions before the handshake
    __shared__ int is_last;
    if (t == 0) is_last = (atomicAdd(red_cnt, 1) == gridDim.x - 1) ? 1 : 0;
    __syncthreads();
    if (is_last && t < 128) {
        // coherent read of device-scope-atomic-written cells
        float s1 = atomicAdd(&sums[t], 0.f);
        float s2 = atomicAdd(&sums[128 + t], 0.f);
        float mean = s1 / (float)N_NODES;
        float var  = s2 / (float)N_NODES - mean * mean;
        float istd = rsqrtf(var + 1e-5f);
        float a = istd * gamma[layer * 128 + t];
        coef[t]       = a;
        coef[128 + t] = beta[layer * 128 + t] - mean * a;
    }
}

// ---------- head: one block per graph, latency-pipelined dot loops ----------
__global__ __launch_bounds__(256) void head_kernel(
    const float* __restrict__ gsum, const float* __restrict__ coefL,
    const int* __restrict__ batch, const float* __restrict__ emb,
    const float* __restrict__ l1w, const float* __restrict__ l1b,
    const float* __restrict__ l2w, const float* __restrict__ l2b,
    const float* __restrict__ l4w, const float* __restrict__ l4b,
    float* __restrict__ out) {
    __shared__ float z[576];
    __shared__ float z1[256];
    __shared__ float z2h[2][128];
    __shared__ float z2[128];
    __shared__ float zr[128][10];
    __shared__ float inv_cnt;
    int g = blockIdx.x;
    int tid = threadIdx.x;
    if (tid == 0) {
        int lo = 0, hi = N_NODES;
        while (lo < hi) { int m = (lo + hi) >> 1; if (batch[m] < g) lo = m + 1; else hi = m; }
        int s = lo;
        lo = 0; hi = N_NODES;
        while (lo < hi) { int m = (lo + hi) >> 1; if (batch[m] < g + 1) lo = m + 1; else hi = m; }
        inv_cnt = 1.0f / fmaxf((float)(lo - s), 1.0f);
    }
    __syncthreads();
    for (int j = tid; j < 512; j += 256) {
        int l = j >> 7, c = j & 127;
        float a = coefL[l * 256 + c], d = coefL[l * 256 + 128 + c];
        z[j] = a * gsum[(size_t)l * NGRAPH * 128 + g * 128 + c] * inv_cnt + d;
    }
    if (tid < 64) z[512 + tid] = emb[g * 64 + tid];
    __syncthreads();
    {   // z1[256] = relu(z[576] @ l1w + b), 16-wide batched loads
        float acc = l1b[tid];
        for (int j0 = 0; j0 < 576; j0 += 16) {
            float lw[16];
#pragma unroll
            for (int t = 0; t < 16; t++) lw[t] = l1w[(j0 + t) * 256 + tid];
#pragma unroll
            for (int t = 0; t < 16; t++) acc += z[j0 + t] * lw[t];
        }
        z1[tid] = fmaxf(acc, 0.f);
    }
    __syncthreads();
    {   // z2[128] = relu(z1[256] @ l2w + b), split-K over 2 halves
        int c2 = tid & 127, half = tid >> 7;
        float acc = 0.f;
        int jb = half * 128;
        for (int j0 = 0; j0 < 128; j0 += 8) {
            float lw[8];
#pragma unroll
            for (int t = 0; t < 8; t++) lw[t] = l2w[(jb + j0 + t) * 128 + c2];
#pragma unroll
            for (int t = 0; t < 8; t++) acc += z1[jb + j0 + t] * lw[t];
        }
        z2h[half][c2] = acc;
    }
    __syncthreads();
    if (tid < 128) z2[tid] = fmaxf(z2h[0][tid] + z2h[1][tid] + l2b[tid], 0.f);
    __syncthreads();
    if (tid < 128) {
        float zv = z2[tid];
        const float* wr = l4w + tid * 10;
#pragma unroll
        for (int c = 0; c < 10; c++) zr[tid][c] = zv * wr[c];
    }
    __syncthreads();
    for (int s = 64; s >= 1; s >>= 1) {
        if (tid < s) {
#pragma unroll
            for (int c = 0; c < 10; c++) zr[tid][c] += zr[tid + s][c];
        }
        __syncthreads();
    }
    if (tid == 0) {
        float z3s[10];
#pragma unroll
        for (int c = 0; c < 10; c++) z3s[c] = zr[0][c] + l4b[c];
        float m = z3s[0];
        for (int i = 1; i < 10; i++) m = fmaxf(m, z3s[i]);
        float se = 0.f;
        for (int i = 0; i < 10; i++) se += expf(z3s[i] - m);
        float lse = m + logf(se);
        for (int i = 0; i < 10; i++) out[g * 10 + i] = z3s[i] - lse;
    }
}

extern "C" void kernel_launch(void* const* d_in, const int* in_sizes, int n_in,
                              void* d_out, int out_size, void* d_ws, size_t ws_size,
                              hipStream_t stream) {
    (void)in_sizes; (void)n_in; (void)out_size; (void)ws_size;
    const float* x0   = (const float*)d_in[0];
    const int* ei     = (const int*)d_in[1];
    const int* src    = ei;
    const int* dst    = ei + N_EDGES;
    const int* batch  = (const int*)d_in[2];
    const float* emb  = (const float*)d_in[3];
    const float* eps  = (const float*)d_in[4];
    const float* W1   = (const float*)d_in[5];
    const float* b1   = (const float*)d_in[6];
    const float* W2   = (const float*)d_in[7];
    const float* b2   = (const float*)d_in[8];
    const float* gamma= (const float*)d_in[9];
    const float* beta = (const float*)d_in[10];
    const float* l1w  = (const float*)d_in[11];
    const float* l1b  = (const float*)d_in[12];
    const float* l2w  = (const float*)d_in[13];
    const float* l2b  = (const float*)d_in[14];
    const float* l4w  = (const float*)d_in[15];
    const float* l4b  = (const float*)d_in[16];

    char* ws = (char*)d_ws;
    size_t off = 0;
    auto alloc = [&](size_t bytes) -> char* {
        char* p = ws + off; off += (bytes + 255) & ~(size_t)255; return p;
    };
    // single zero region: deg + cursor + red_cnt + sumsL + gsumL (contiguous)
    int* deg    = (int*)alloc(N_NODES * 4);
    int* cursor = (int*)alloc(N_NODES * 4);
    int* red_cnt = (int*)alloc(NLAYER * 4);
    float* sumsL = (float*)alloc(NLAYER * 256 * 4);
    float* gsumL = (float*)alloc((size_t)NLAYER * NGRAPH * 128 * 4);
    size_t zero_len = (char*)gsumL - (char*)deg + (size_t)NLAYER * NGRAPH * 128 * 4;
    int* rowp   = (int*)alloc((N_NODES + 1) * 4);
    int* bscan  = (int*)alloc(N_NODES * 4);
    int* bsum   = (int*)alloc(SCAN_NB * 4);
    int* boff   = (int*)alloc(SCAN_NB * 4);
    int* col    = (int*)alloc(N_EDGES * 4);
    u32* xbf    = (u32*)alloc((size_t)N_NODES * 64 * 4);
    u32* agg    = (u32*)alloc((size_t)N_NODES * 64 * 4);
    u32* h2a    = (u32*)alloc((size_t)N_NODES * 64 * 4);
    u32* h2b    = (u32*)alloc((size_t)N_NODES * 64 * 4);
    short* W1t  = (short*)alloc((size_t)NLAYER * 128 * 128 * 2);
    short* W2t  = (short*)alloc((size_t)NLAYER * 128 * 128 * 2);
    float* partial = (float*)alloc((size_t)NBLK_MLP * 256 * 4);
    float* coefL = (float*)alloc(NLAYER * 256 * 4);

    hipMemsetAsync(deg, 0, zero_len, stream);

    cvt_x<<<(N_NODES * 64 + 255) / 256, 256, 0, stream>>>((const float2*)x0, xbf);
    {
        dim3 gw(128, NLAYER, 2);
        cvt_w<<<gw, 128, 0, stream>>>(W1, W2, W1t, W2t);
    }
    count_deg<<<(N_EDGES + 255) / 256, 256, 0, stream>>>(dst, deg);
    scan_l1<<<SCAN_NB, 256, 0, stream>>>(deg, bscan, bsum);
    scan_l2<<<1, 256, 0, stream>>>(bsum, boff);
    scan_l3<<<SCAN_NB, 256, 0, stream>>>(bscan, boff, rowp);
    fill_csr<<<(N_EDGES + 255) / 256, 256, 0, stream>>>(src, dst, rowp, cursor, col);

    const u32* xin = xbf;
    for (int l = 0; l < NLAYER; ++l) {
        u32* h2 = (l & 1) ? h2b : h2a;
        const float* coef_prev = (l == 0) ? nullptr : (coefL + (l - 1) * 256);
        agg_kernel<<<(N_NODES + 3) / 4, 256, 0, stream>>>(
            xin, coef_prev, rowp, col, eps, l, agg);
        mlp_fused<<<NBLK_MLP, 256, 0, stream>>>(
            (const short*)agg, W1t + (size_t)l * 16384, b1 + l * 128,
            W2t + (size_t)l * 16384, b2 + l * 128, (short*)h2, batch,
            partial, gsumL + (size_t)l * NGRAPH * 128, N_NODES);
        reduce_finalize<<<RED_B, 256, 0, stream>>>(
            partial, sumsL + l * 256, red_cnt + l, gamma, beta, l,
            coefL + l * 256);
        xin = h2;
    }
    head_kernel<<<NGRAPH, 256, 0, stream>>>(gsumL, coefL, batch, emb,
                                            l1w, l1b, l2w, l2b, l4w, l4b,
                                            (float*)d_out);
}

// Round 15
// 410.190 us; speedup vs baseline: 1.3006x; 1.0144x over previous
//
#include <hip/hip_runtime.h>
#include <cstdint>
#include <cstddef>

#define N_NODES 50000
#define N_EDGES 600000
#define NLAYER  4
#define NGRAPH  64
#define SCAN_NB 196   // ceil(50000/256)
#define NBLK_MLP ((N_NODES + 127) / 128)   // 391, 128-row MLP tiles
#define RED_B    ((NBLK_MLP + 12) / 13)    // 31 reduce blocks x 13 partials

typedef unsigned int   u32;
typedef unsigned short u16;
typedef unsigned char  u8;
typedef float f32x4  __attribute__((ext_vector_type(4)));
typedef short bf16x8 __attribute__((ext_vector_type(8)));

// ---------- bf16 helpers ----------
__device__ __forceinline__ float bf1(u16 u)  { return __uint_as_float(((u32)u) << 16); }
__device__ __forceinline__ float bflo(u32 u) { return __uint_as_float(u << 16); }
__device__ __forceinline__ float bfhi(u32 u) { return __uint_as_float(u & 0xffff0000u); }
__device__ __forceinline__ u16 f2bf(float f) {
    u32 x = __float_as_uint(f);
    u32 r = x + 0x7fffu + ((x >> 16) & 1u);   // RNE
    return (u16)(r >> 16);
}
__device__ __forceinline__ u32 pack2(float a, float b) {
    return (u32)f2bf(a) | ((u32)f2bf(b) << 16);
}

// ---------- fp8 e4m3 helpers (HW convert; format self-consistent pack<->unpack) ----------
__device__ __forceinline__ float fp8b0(u32 u) { return __builtin_amdgcn_cvt_f32_fp8(u, 0); }
__device__ __forceinline__ float fp8b1(u32 u) { return __builtin_amdgcn_cvt_f32_fp8(u, 1); }
__device__ __forceinline__ u32 pk_fp8(float a, float b) {
    return (u32)__builtin_amdgcn_cvt_pk_fp8_f32(a, b, 0, false);   // bytes 0,1
}

// ---------- dtype conversion: x fp32 -> fp8 rows ----------
__global__ __launch_bounds__(256) void cvt_x(const float4* __restrict__ x,
                                             u32* __restrict__ xf8) {
    int i = blockIdx.x * 256 + threadIdx.x;   // over N*32 u32s (4 fp8 each)
    if (i < N_NODES * 32) {
        float4 v = x[i];
        u32 r = pk_fp8(v.x, v.y);
        r = (u32)__builtin_amdgcn_cvt_pk_fp8_f32(v.z, v.w, (int)r, true);  // bytes 2,3
        xf8[i] = r;
    }
}

// W: [L][128 k][128 n] fp32 -> Wt: [L][128 n][128 k] bf16; z selects W1/W2
__global__ __launch_bounds__(128) void cvt_w(const float* __restrict__ W1,
                                             const float* __restrict__ W2,
                                             short* __restrict__ W1t,
                                             short* __restrict__ W2t) {
    int l = blockIdx.y, n = blockIdx.x, k = threadIdx.x;
    const float* W = blockIdx.z ? W2 : W1;
    short* Wt      = blockIdx.z ? W2t : W1t;
    Wt[((size_t)l * 128 + n) * 128 + k] = (short)f2bf(W[((size_t)l * 128 + k) * 128 + n]);
}

// ---------- CSR build ----------
__global__ void count_deg(const int* __restrict__ dst, int* __restrict__ deg) {
    int e = blockIdx.x * 256 + threadIdx.x;
    if (e < N_EDGES) atomicAdd(&deg[dst[e]], 1);
}

__global__ __launch_bounds__(256) void scan_l1(const int* __restrict__ deg,
                                               int* __restrict__ bscan,
                                               int* __restrict__ bsum) {
    __shared__ int sd[256];
    int tid = threadIdx.x;
    int i = blockIdx.x * 256 + tid;
    int v = (i < N_NODES) ? deg[i] : 0;
    sd[tid] = v; __syncthreads();
#pragma unroll
    for (int off = 1; off < 256; off <<= 1) {
        int t = (tid >= off) ? sd[tid - off] : 0;
        __syncthreads();
        sd[tid] += t; __syncthreads();
    }
    if (i < N_NODES) bscan[i] = sd[tid];
    if (tid == 255) bsum[blockIdx.x] = sd[255];
}

__global__ __launch_bounds__(256) void scan_l2(const int* __restrict__ bsum,
                                               int* __restrict__ boff) {
    __shared__ int sd[256];
    int tid = threadIdx.x;
    int v = (tid < SCAN_NB) ? bsum[tid] : 0;
    sd[tid] = v; __syncthreads();
#pragma unroll
    for (int off = 1; off < 256; off <<= 1) {
        int t = (tid >= off) ? sd[tid - off] : 0;
        __syncthreads();
        sd[tid] += t; __syncthreads();
    }
    if (tid < SCAN_NB) boff[tid] = sd[tid] - v;
}

__global__ __launch_bounds__(256) void scan_l3(const int* __restrict__ bscan,
                                               const int* __restrict__ boff,
                                               int* __restrict__ rowp) {
    int i = blockIdx.x * 256 + threadIdx.x;
    if (i == 0) rowp[0] = 0;
    if (i < N_NODES) rowp[i + 1] = bscan[i] + boff[blockIdx.x];
}

__global__ void fill_csr(const int* __restrict__ src, const int* __restrict__ dst,
                         const int* __restrict__ rowp, int* __restrict__ cursor,
                         int* __restrict__ col) {
    int e = blockIdx.x * 256 + threadIdx.x;
    if (e < N_EDGES) {
        int d = dst[e];
        int pos = atomicAdd(&cursor[d], 1);
        col[rowp[d] + pos] = src[e];
    }
}

// ---------- GIN aggregation (fp8 gather, fp32 accum, analytic BN of prev layer) ----------
// one wave per node; 8-deep pipelined edge loop; lane covers cols {2*lane, 2*lane+1}
// via one u16 (2 fp8) load -> 128 B/row (half of bf16)
__global__ __launch_bounds__(256) void agg_kernel(
    const u16* __restrict__ xin,      // [N][64] u16 (128 fp8)
    const float* __restrict__ coef,   // nullable [256]
    const int* __restrict__ rowp, const int* __restrict__ col,
    const float* __restrict__ eps_all, int layer,
    u32* __restrict__ agg) {          // [N][64] u32 (128 bf16)
    int node = blockIdx.x * 4 + (threadIdx.x >> 6);
    int lane = threadIdx.x & 63;
    if (node >= N_NODES) return;
    float a0 = 1.f, a1 = 1.f, d0 = 0.f, d1 = 0.f;
    if (coef) {
        a0 = coef[2 * lane];       a1 = coef[2 * lane + 1];
        d0 = coef[128 + 2 * lane]; d1 = coef[128 + 2 * lane + 1];
    }
    float ep = 1.0f + eps_all[layer];
    u32 v = xin[(size_t)node * 64 + lane];
    int k0 = rowp[node], k1 = rowp[node + 1];
    float s0 = 0.f, s1 = 0.f;
    int k = k0;
    int cc[8];
    if (k < k1) {
#pragma unroll
        for (int t = 0; t < 8; t++) cc[t] = col[min(k + t, k1 - 1)];
    }
    while (k < k1) {
        int idx[8];
#pragma unroll
        for (int t = 0; t < 8; t++) idx[t] = cc[t];
        int kn = k + 8;
        if (kn < k1) {
#pragma unroll
            for (int t = 0; t < 8; t++) cc[t] = col[min(kn + t, k1 - 1)];
        }
#pragma unroll
        for (int t = 0; t < 8; t++) {
            u32 u = xin[(size_t)idx[t] * 64 + lane];
            float w = (k + t < k1) ? 1.f : 0.f;
            s0 += w * fp8b0(u); s1 += w * fp8b1(u);
        }
        k = kn;
    }
    float deg = (float)(k1 - k0);
    float r0 = ep * (a0 * fp8b0(v) + d0) + a0 * s0 + deg * d0;
    float r1 = ep * (a1 * fp8b1(v) + d1) + a1 * s1 + deg * d1;
    agg[(size_t)node * 64 + lane] = pack2(r0, r1);
}

// ---------- fused MLP + BN-stats + per-graph pooling (round-10 config; fp8 H2 out) ----------
#define H1_STRIDE 136
__global__ __launch_bounds__(256) void mlp_fused(
    const short* __restrict__ A,
    const short* __restrict__ W1t, const float* __restrict__ b1,
    const short* __restrict__ W2t, const float* __restrict__ b2,
    u8* __restrict__ H2, const int* __restrict__ batch,
    float* __restrict__ partial, float* __restrict__ gsum, int M) {
    __shared__ alignas(16) short h1s[128 * H1_STRIDE];   // 34816 B, reused as scratch
    __shared__ int sh_ga, sh_gb, sh_split;
    int tid  = threadIdx.x;
    int wave = tid >> 6, lane = tid & 63;
    int ln15 = lane & 15, quad = lane >> 4;
    int m0blk = blockIdx.x * 128;
    int m0 = m0blk + wave * 32;
    const bf16x8 zz = {0, 0, 0, 0, 0, 0, 0, 0};

    if (tid == 0) {
        int rlo = m0blk, rhi = min(m0blk + 127, M - 1);
        int ga = batch[rlo], gb = batch[rhi];
        int split = m0blk + 128;
        if (ga != gb) {
            int lo = rlo, hi = rhi;
            while (lo + 1 < hi) { int mid = (lo + hi) >> 1; if (batch[mid] == ga) lo = mid; else hi = mid; }
            split = hi;
        }
        sh_ga = ga; sh_gb = gb; sh_split = split;
    }

    bf16x8 a[2][4];
#pragma unroll
    for (int rt = 0; rt < 2; rt++) {
        int row = m0 + rt * 16 + ln15;
        const short* rp = A + (size_t)row * 128 + quad * 8;
        bool ok = row < M;
#pragma unroll
        for (int s = 0; s < 4; s++)
            a[rt][s] = ok ? *(const bf16x8*)(rp + s * 32) : zz;
    }
#pragma unroll
    for (int ct = 0; ct < 8; ct++) {
        const short* wp = W1t + (size_t)(ct * 16 + ln15) * 128 + quad * 8;
        bf16x8 b[4];
#pragma unroll
        for (int s = 0; s < 4; s++) b[s] = *(const bf16x8*)(wp + s * 32);
        float bias = b1[ct * 16 + ln15];
#pragma unroll
        for (int rt = 0; rt < 2; rt++) {
            f32x4 acc = {0.f, 0.f, 0.f, 0.f};
#pragma unroll
            for (int s = 0; s < 4; s++)
                acc = __builtin_amdgcn_mfma_f32_16x16x32_bf16(a[rt][s], b[s], acc, 0, 0, 0);
#pragma unroll
            for (int i = 0; i < 4; i++) {
                float v = fmaxf(acc[i] + bias, 0.f);
                int lr = wave * 32 + rt * 16 + quad * 4 + i;
                h1s[lr * H1_STRIDE + ct * 16 + ln15] = (short)f2bf(v);
            }
        }
    }
    __syncthreads();
    bf16x8 c[2][4];
#pragma unroll
    for (int rt = 0; rt < 2; rt++) {
        const short* rp = h1s + (size_t)(wave * 32 + rt * 16 + ln15) * H1_STRIDE + quad * 8;
#pragma unroll
        for (int s = 0; s < 4; s++) c[rt][s] = *(const bf16x8*)(rp + s * 32);
    }
    int gsplit = sh_split;
    float sAcc[8], qAcc[8], pAcc[8];
#pragma unroll
    for (int ct = 0; ct < 8; ct++) { sAcc[ct] = 0.f; qAcc[ct] = 0.f; pAcc[ct] = 0.f; }
#pragma unroll
    for (int ct = 0; ct < 8; ct++) {
        const short* wp = W2t + (size_t)(ct * 16 + ln15) * 128 + quad * 8;
        bf16x8 b[4];
#pragma unroll
        for (int s = 0; s < 4; s++) b[s] = *(const bf16x8*)(wp + s * 32);
        float bias = b2[ct * 16 + ln15];
#pragma unroll
        for (int rt = 0; rt < 2; rt++) {
            f32x4 acc = {0.f, 0.f, 0.f, 0.f};
#pragma unroll
            for (int s = 0; s < 4; s++)
                acc = __builtin_amdgcn_mfma_f32_16x16x32_bf16(c[rt][s], b[s], acc, 0, 0, 0);
            int colx = ct * 16 + ln15;
#pragma unroll
            for (int i = 0; i < 4; i++) {
                int row = m0 + rt * 16 + quad * 4 + i;
                float v = fmaxf(acc[i] + bias, 0.f);
                if (row < M) H2[(size_t)row * 128 + colx] = (u8)(pk_fp8(v, v) & 0xffu);
                float vm = (row < M) ? v : 0.f;   // stats/pool use EXACT fp32 value
                sAcc[ct] += vm; qAcc[ct] += vm * vm;
                if (row < gsplit) pAcc[ct] += vm;
            }
        }
    }
    __syncthreads();
    float* scr = (float*)h1s;          // [3][16][128]
    int slice = wave * 4 + quad;
#pragma unroll
    for (int ct = 0; ct < 8; ct++) {
        int colx = ct * 16 + ln15;
        scr[(0 * 16 + slice) * 128 + colx] = sAcc[ct];
        scr[(1 * 16 + slice) * 128 + colx] = qAcc[ct];
        scr[(2 * 16 + slice) * 128 + colx] = pAcc[ct];
    }
    __syncthreads();
    if (tid < 128) {
        float ss = 0.f, qq = 0.f, pa = 0.f;
#pragma unroll
        for (int sl = 0; sl < 16; sl++) {
            ss += scr[(0 * 16 + sl) * 128 + tid];
            qq += scr[(1 * 16 + sl) * 128 + tid];
            pa += scr[(2 * 16 + sl) * 128 + tid];
        }
        partial[(size_t)blockIdx.x * 256 + tid]       = ss;
        partial[(size_t)blockIdx.x * 256 + 128 + tid] = qq;
        int ga = sh_ga, gb = sh_gb;
        atomicAdd(&gsum[ga * 128 + tid], pa);
        if (gb != ga) atomicAdd(&gsum[gb * 128 + tid], ss - pa);
    }
}

// ---------- fold block partials into sums + last-block BN finalize ----------
__global__ __launch_bounds__(256) void reduce_finalize(
    const float* __restrict__ partial, float* __restrict__ sums,
    int* __restrict__ red_cnt,
    const float* __restrict__ gamma, const float* __restrict__ beta,
    int layer, float* __restrict__ coef) {
    int t = threadIdx.x;
    int b0 = blockIdx.x * 13, b1 = min(b0 + 13, NBLK_MLP);
    if (b0 < NBLK_MLP) {
        float acc = 0.f;
        for (int b = b0; b < b1; b++) acc += partial[(size_t)b * 256 + t];
        atomicAdd(&sums[t], acc);
    }
    __threadfence();
    __shared__ int is_last;
    if (t == 0) is_last = (atomicAdd(red_cnt, 1) == gridDim.x - 1) ? 1 : 0;
    __syncthreads();
    if (is_last && t < 128) {
        float s1 = atomicAdd(&sums[t], 0.f);
        float s2 = atomicAdd(&sums[128 + t], 0.f);
        float mean = s1 / (float)N_NODES;
        float var  = s2 / (float)N_NODES - mean * mean;
        float istd = rsqrtf(var + 1e-5f);
        float a = istd * gamma[layer * 128 + t];
        coef[t]       = a;
        coef[128 + t] = beta[layer * 128 + t] - mean * a;
    }
}

// ---------- head: one block per graph, latency-pipelined dot loops ----------
__global__ __launch_bounds__(256) void head_kernel(
    const float* __restrict__ gsum, const float* __restrict__ coefL,
    const int* __restrict__ batch, const float* __restrict__ emb,
    const float* __restrict__ l1w, const float* __restrict__ l1b,
    const float* __restrict__ l2w, const float* __restrict__ l2b,
    const float* __restrict__ l4w, const float* __restrict__ l4b,
    float* __restrict__ out) {
    __shared__ float z[576];
    __shared__ float z1[256];
    __shared__ float z2h[2][128];
    __shared__ float z2[128];
    __shared__ float zr[128][10];
    __shared__ float inv_cnt;
    int g = blockIdx.x;
    int tid = threadIdx.x;
    if (tid == 0) {
        int lo = 0, hi = N_NODES;
        while (lo < hi) { int m = (lo + hi) >> 1; if (batch[m] < g) lo = m + 1; else hi = m; }
        int s = lo;
        lo = 0; hi = N_NODES;
        while (lo < hi) { int m = (lo + hi) >> 1; if (batch[m] < g + 1) lo = m + 1; else hi = m; }
        inv_cnt = 1.0f / fmaxf((float)(lo - s), 1.0f);
    }
    __syncthreads();
    for (int j = tid; j < 512; j += 256) {
        int l = j >> 7, c = j & 127;
        float a = coefL[l * 256 + c], d = coefL[l * 256 + 128 + c];
        z[j] = a * gsum[(size_t)l * NGRAPH * 128 + g * 128 + c] * inv_cnt + d;
    }
    if (tid < 64) z[512 + tid] = emb[g * 64 + tid];
    __syncthreads();
    {
        float acc = l1b[tid];
        for (int j0 = 0; j0 < 576; j0 += 16) {
            float lw[16];
#pragma unroll
            for (int t = 0; t < 16; t++) lw[t] = l1w[(j0 + t) * 256 + tid];
#pragma unroll
            for (int t = 0; t < 16; t++) acc += z[j0 + t] * lw[t];
        }
        z1[tid] = fmaxf(acc, 0.f);
    }
    __syncthreads();
    {
        int c2 = tid & 127, half = tid >> 7;
        float acc = 0.f;
        int jb = half * 128;
        for (int j0 = 0; j0 < 128; j0 += 8) {
            float lw[8];
#pragma unroll
            for (int t = 0; t < 8; t++) lw[t] = l2w[(jb + j0 + t) * 128 + c2];
#pragma unroll
            for (int t = 0; t < 8; t++) acc += z1[jb + j0 + t] * lw[t];
        }
        z2h[half][c2] = acc;
    }
    __syncthreads();
    if (tid < 128) z2[tid] = fmaxf(z2h[0][tid] + z2h[1][tid] + l2b[tid], 0.f);
    __syncthreads();
    if (tid < 128) {
        float zv = z2[tid];
        const float* wr = l4w + tid * 10;
#pragma unroll
        for (int c = 0; c < 10; c++) zr[tid][c] = zv * wr[c];
    }
    __syncthreads();
    for (int s = 64; s >= 1; s >>= 1) {
        if (tid < s) {
#pragma unroll
            for (int c = 0; c < 10; c++) zr[tid][c] += zr[tid + s][c];
        }
        __syncthreads();
    }
    if (tid == 0) {
        float z3s[10];
#pragma unroll
        for (int c = 0; c < 10; c++) z3s[c] = zr[0][c] + l4b[c];
        float m = z3s[0];
        for (int i = 1; i < 10; i++) m = fmaxf(m, z3s[i]);
        float se = 0.f;
        for (int i = 0; i < 10; i++) se += expf(z3s[i] - m);
        float lse = m + logf(se);
        for (int i = 0; i < 10; i++) out[g * 10 + i] = z3s[i] - lse;
    }
}

extern "C" void kernel_launch(void* const* d_in, const int* in_sizes, int n_in,
                              void* d_out, int out_size, void* d_ws, size_t ws_size,
                              hipStream_t stream) {
    (void)in_sizes; (void)n_in; (void)out_size; (void)ws_size;
    const float* x0   = (const float*)d_in[0];
    const int* ei     = (const int*)d_in[1];
    const int* src    = ei;
    const int* dst    = ei + N_EDGES;
    const int* batch  = (const int*)d_in[2];
    const float* emb  = (const float*)d_in[3];
    const float* eps  = (const float*)d_in[4];
    const float* W1   = (const float*)d_in[5];
    const float* b1   = (const float*)d_in[6];
    const float* W2   = (const float*)d_in[7];
    const float* b2   = (const float*)d_in[8];
    const float* gamma= (const float*)d_in[9];
    const float* beta = (const float*)d_in[10];
    const float* l1w  = (const float*)d_in[11];
    const float* l1b  = (const float*)d_in[12];
    const float* l2w  = (const float*)d_in[13];
    const float* l2b  = (const float*)d_in[14];
    const float* l4w  = (const float*)d_in[15];
    const float* l4b  = (const float*)d_in[16];

    char* ws = (char*)d_ws;
    size_t off = 0;
    auto alloc = [&](size_t bytes) -> char* {
        char* p = ws + off; off += (bytes + 255) & ~(size_t)255; return p;
    };
    // single zero region: deg + cursor + red_cnt + sumsL + gsumL (contiguous)
    int* deg    = (int*)alloc(N_NODES * 4);
    int* cursor = (int*)alloc(N_NODES * 4);
    int* red_cnt = (int*)alloc(NLAYER * 4);
    float* sumsL = (float*)alloc(NLAYER * 256 * 4);
    float* gsumL = (float*)alloc((size_t)NLAYER * NGRAPH * 128 * 4);
    size_t zero_len = (char*)gsumL - (char*)deg + (size_t)NLAYER * NGRAPH * 128 * 4;
    int* rowp   = (int*)alloc((N_NODES + 1) * 4);
    int* bscan  = (int*)alloc(N_NODES * 4);
    int* bsum   = (int*)alloc(SCAN_NB * 4);
    int* boff   = (int*)alloc(SCAN_NB * 4);
    int* col    = (int*)alloc(N_EDGES * 4);
    u8* xf8     = (u8*)alloc((size_t)N_NODES * 128);      // x in fp8
    u8* h2a     = (u8*)alloc((size_t)N_NODES * 128);      // h2 fp8 double-buffer
    u8* h2b     = (u8*)alloc((size_t)N_NODES * 128);
    u32* agg    = (u32*)alloc((size_t)N_NODES * 64 * 4);  // agg bf16 (MFMA A input)
    short* W1t  = (short*)alloc((size_t)NLAYER * 128 * 128 * 2);
    short* W2t  = (short*)alloc((size_t)NLAYER * 128 * 128 * 2);
    float* partial = (float*)alloc((size_t)NBLK_MLP * 256 * 4);
    float* coefL = (float*)alloc(NLAYER * 256 * 4);

    hipMemsetAsync(deg, 0, zero_len, stream);

    cvt_x<<<(N_NODES * 32 + 255) / 256, 256, 0, stream>>>((const float4*)x0, (u32*)xf8);
    {
        dim3 gw(128, NLAYER, 2);
        cvt_w<<<gw, 128, 0, stream>>>(W1, W2, W1t, W2t);
    }
    count_deg<<<(N_EDGES + 255) / 256, 256, 0, stream>>>(dst, deg);
    scan_l1<<<SCAN_NB, 256, 0, stream>>>(deg, bscan, bsum);
    scan_l2<<<1, 256, 0, stream>>>(bsum, boff);
    scan_l3<<<SCAN_NB, 256, 0, stream>>>(bscan, boff, rowp);
    fill_csr<<<(N_EDGES + 255) / 256, 256, 0, stream>>>(src, dst, rowp, cursor, col);

    const u8* xin = xf8;
    for (int l = 0; l < NLAYER; ++l) {
        u8* h2 = (l & 1) ? h2b : h2a;
        const float* coef_prev = (l == 0) ? nullptr : (coefL + (l - 1) * 256);
        agg_kernel<<<(N_NODES + 3) / 4, 256, 0, stream>>>(
            (const u16*)xin, coef_prev, rowp, col, eps, l, agg);
        mlp_fused<<<NBLK_MLP, 256, 0, stream>>>(
            (const short*)agg, W1t + (size_t)l * 16384, b1 + l * 128,
            W2t + (size_t)l * 16384, b2 + l * 128, h2, batch,
            partial, gsumL + (size_t)l * NGRAPH * 128, N_NODES);
        reduce_finalize<<<RED_B, 256, 0, stream>>>(
            partial, sumsL + l * 256, red_cnt + l, gamma, beta, l,
            coefL + l * 256);
        xin = h2;
    }
    head_kernel<<<NGRAPH, 256, 0, stream>>>(gsumL, coefL, batch, emb,
                                            l1w, l1b, l2w, l2b, l4w, l4b,
                                            (float*)d_out);
}